// Round 5
// baseline (995.909 us; speedup 1.0000x reference)
//
#include <hip/hip_runtime.h>
#include <math.h>

#define BN   2
#define CIN  96
#define HH   40
#define WW   40
#define LL   1600
#define DIN  192
#define NS   16
#define RR   6
#define KK   4
#define CH   25   // chunk length per lane (LL/64)

__device__ __forceinline__ float sigmoidf_(float x){ return 1.0f/(1.0f+expf(-x)); }
__device__ __forceinline__ float softplusf_(float x){ return x > 20.0f ? x : log1pf(expf(x)); }
__device__ __forceinline__ float softplus_fast(float x){
  return x > 20.0f ? x : __logf(1.0f + __expf(x));
}

// ---------------- K1: in_proj (1x1) for both modalities ----------------
// grid: (L/16, 2*B), block 256. xproj layout [mb][o][p]
__global__ void k_inproj(const float* __restrict__ x_rgb, const float* __restrict__ x_e,
                         const float* __restrict__ w_rgb, const float* __restrict__ w_e,
                         float* __restrict__ xproj){
  __shared__ float xin[16][100];          // [px][c], padded row
  int l0 = blockIdx.x * 16;
  int mb = blockIdx.y;                    // m*BN + b
  int m = mb / BN, b = mb % BN;
  const float* xsrc = (m == 0 ? x_rgb : x_e) + (size_t)b * CIN * LL;
  const float* w    = (m == 0 ? w_rgb : w_e);
  for (int idx = threadIdx.x; idx < CIN * 16; idx += 256){
    int c = idx >> 4, px = idx & 15;
    xin[px][c] = xsrc[c * LL + l0 + px];
  }
  __syncthreads();
  int px = threadIdx.x & 15;
  int o0 = (threadIdx.x >> 4) * 12;       // 16 groups x 12 outputs
  float acc[12];
  #pragma unroll
  for (int i = 0; i < 12; ++i) acc[i] = 0.f;
  const float4* xv = reinterpret_cast<const float4*>(xin[px]);
  for (int cc = 0; cc < CIN / 4; ++cc){
    float4 x4 = xv[cc];
    #pragma unroll
    for (int i = 0; i < 12; ++i){
      float4 w4 = *reinterpret_cast<const float4*>(w + (o0 + i) * CIN + cc * 4);
      acc[i] += w4.x * x4.x + w4.y * x4.y + w4.z * x4.z + w4.w * x4.w;
    }
  }
  #pragma unroll
  for (int i = 0; i < 12; ++i)
    xproj[((size_t)mb * DIN + o0 + i) * LL + l0 + px] = acc[i];
}

// ------ K2: depthwise 3x3 + bias + SiLU; emit x_act, x_actT, u_ch, SE mean ---
// grid: (DIN, 2*B), block 256
__global__ void k_conv(const float* __restrict__ xproj, const float* __restrict__ conv_w,
                       const float* __restrict__ conv_b, float* __restrict__ x_act,
                       float* __restrict__ x_actT, float* __restrict__ u_chA,
                       float* __restrict__ u_chT, float* __restrict__ sq){
  __shared__ float pl[LL];
  __shared__ float sact[LL + HH];    // padded: index l + l/40
  __shared__ float red[4];
  int d  = blockIdx.x;
  int mb = blockIdx.y;
  const float* src = xproj + ((size_t)mb * DIN + d) * LL;
  for (int p = threadIdx.x; p < LL; p += blockDim.x) pl[p] = src[p];
  __syncthreads();
  float cw[9];
  #pragma unroll
  for (int j = 0; j < 9; ++j) cw[j] = conv_w[d * 9 + j];
  float bias = conv_b[d];
  float* dst = x_act + ((size_t)mb * DIN + d) * LL;
  float lsum = 0.f;
  for (int p = threadIdx.x; p < LL; p += blockDim.x){
    int py = p / WW, px = p % WW;
    float acc = bias;
    #pragma unroll
    for (int dy = -1; dy <= 1; ++dy){
      int yy = py + dy;
      if (yy < 0 || yy >= HH) continue;
      #pragma unroll
      for (int dx = -1; dx <= 1; ++dx){
        int xx = px + dx;
        if (xx < 0 || xx >= WW) continue;
        acc += cw[(dy + 1) * 3 + (dx + 1)] * pl[yy * WW + xx];
      }
    }
    float s = acc * sigmoidf_(acc);
    dst[p] = s;
    sact[p + p / WW] = s;
    lsum += s;
  }
  #pragma unroll
  for (int off = 32; off; off >>= 1) lsum += __shfl_down(lsum, off);
  if ((threadIdx.x & 63) == 0) red[threadIdx.x >> 6] = lsum;
  __syncthreads();
  if (threadIdx.x == 0)
    sq[mb * DIN + d] = (red[0] + red[1] + red[2] + red[3]) * (1.0f / LL);
  size_t po = ((size_t)mb * DIN + d) * LL;
  float* dstT = x_actT + po;
  float* uA   = u_chA + po;
  float* uT   = u_chT + po;
  for (int q = threadIdx.x; q < LL; q += blockDim.x){
    // transposed plane (row-major in q)
    int lt = (q % WW) * WW + q / WW;
    dstT[q] = sact[lt + lt / WW];
    // chunk-order planes: q = s*64+g  <->  l = g*25+s
    int l = (q & 63) * CH + (q >> 6);
    uA[q] = sact[l + l / WW];
    int pt = (l % WW) * WW + l / WW;
    uT[q] = sact[pt + pt / WW];
  }
}

// ------ K3: x_proj -> tdt_ch [mbk][r][q]; B/C in CHUNK layout [mbk][q][n] ---
// grid: (L/64, K, 2*B), block 256
__global__ void k_xproj(const float* __restrict__ x_act, const float* __restrict__ x_actT,
                        const float* __restrict__ xp1, const float* __restrict__ xp2,
                        float* __restrict__ tdt_ch, float* __restrict__ B_ch,
                        float* __restrict__ C_ch){
  __shared__ float xs_t[DIN][64];
  int l0 = blockIdx.x * 64;
  int k  = blockIdx.y;
  int mb = blockIdx.z; int m = mb / BN;
  const float* xw = (m == 0 ? xp1 : xp2) + k * 38 * DIN;
  const float* xa = ((k & 1) ? x_actT : x_act) + (size_t)mb * DIN * LL;
  bool rev = (k >= 2);
  for (int idx = threadIdx.x; idx < DIN * 64; idx += blockDim.x){
    int dd = idx >> 6, ll = idx & 63;
    int l = l0 + ll; if (rev) l = LL - 1 - l;
    xs_t[dd][ll] = xa[dd * LL + l];
  }
  __syncthreads();
  int mbk = mb * KK + k;
  for (int oidx = threadIdx.x; oidx < 38 * 64; oidx += blockDim.x){
    int c = oidx >> 6, ll = oidx & 63;
    const float* wr = xw + c * DIN;
    float acc = 0.f;
    #pragma unroll 8
    for (int dd = 0; dd < DIN; ++dd) acc += wr[dd] * xs_t[dd][ll];
    int l = l0 + ll;
    int q = (l % CH) * 64 + l / CH;     // chunk-order index
    if (c < RR)            tdt_ch[((size_t)mbk * RR + c) * LL + q] = acc;
    else if (c < RR + NS)  B_ch[((size_t)mbk * LL + q) * NS + (c - RR)] = acc;
    else                   C_ch[((size_t)mbk * LL + q) * NS + (c - RR - NS)] = acc;
  }
}

// ---------------- K4: chunked parallel selective scan, n-split ----------
// 2 waves per chain (each owns 8 of 16 states); dt in registers (pre-loop).
// grid: 1536 blocks of 256 (2 chains/block). y_px layout [chain][pixel]
__global__ void __launch_bounds__(256, 6) k_scan(
    const float* __restrict__ u_chA, const float* __restrict__ u_chT,
    const float* __restrict__ tdt_all, const float* __restrict__ B_ch,
    const float* __restrict__ C_ch,
    const float* __restrict__ Alog1, const float* __restrict__ Alog2,
    const float* __restrict__ D1, const float* __restrict__ D2,
    const float* __restrict__ dtw1, const float* __restrict__ dtb1,
    const float* __restrict__ dtw2, const float* __restrict__ dtb2,
    float* __restrict__ y_px){
  __shared__ float ystage[2][2][LL + HH];   // [chain-in-blk][n-half][pad l]
  int wv   = threadIdx.x >> 6;
  int lane = threadIdx.x & 63;
  int c    = wv >> 1;                       // chain in block
  int nh   = wv & 1;                        // n-half
  int chain = blockIdx.x * 2 + c;           // = (mb*KK + k)*DIN + d
  int d   = chain % DIN;
  int mbk = chain / DIN;
  int k   = mbk % KK;
  int mb  = mbk / KK;
  int m = mb / BN, b = mb % BN;
  int kd = k * DIN + d;
  bool rev = (k >= 2);

  const float* Alog = (m == 0 ? Alog1 : Alog2) + kd * NS + nh * 8;
  float An[8];
  #pragma unroll
  for (int n = 0; n < 8; ++n) An[n] = -__expf(Alog[n]);
  float Dv = (m == 0 ? D2 : D1)[kd];
  const float* dtw = (m == 0 ? dtw1 : dtw2) + kd * RR;
  float w0 = dtw[0], w1 = dtw[1], w2 = dtw[2], w3 = dtw[3], w4 = dtw[4], w5 = dtw[5];
  float dbias = (m == 0 ? dtb1 : dtb2)[kd];

  const float* t0 = tdt_all + (size_t)mbk * RR * LL;    // [r][q] rows
  const float* Bp = B_ch + (size_t)mbk * LL * NS + nh * 8;
  int mbk_o = ((1 - m) * BN + b) * KK + k;              // other modality's C
  const float* Cp = C_ch + (size_t)mbk_o * LL * NS + nh * 8;
  const float* urow = ((k & 1) ? u_chT : u_chA) + ((size_t)mb * DIN + d) * LL;

  // pre-loop: dt for this lane's 25 steps, in registers (computed once)
  float dtv[CH];
  float Sdt = 0.f;
  #pragma unroll
  for (int s = 0; s < CH; ++s){
    int q = s * 64 + lane;
    float dtpre = w0 * t0[q] + w1 * t0[LL + q] + w2 * t0[2 * LL + q]
                + w3 * t0[3 * LL + q] + w4 * t0[4 * LL + q] + w5 * t0[5 * LL + q] + dbias;
    float dt = softplus_fast(dtpre);
    dtv[s] = dt;
    Sdt += dt;
  }

  float h[8];
  #pragma unroll
  for (int n = 0; n < 8; ++n) h[n] = 0.f;

  // phase 1: local chunk scan -> h_local_end (aP comes from Sdt)
  for (int s = 0; s < CH; ++s){
    int q = s * 64 + lane;
    float dt = dtv[s];
    float u  = urow[rev ? (LL - 1 - q) : q];
    float du = dt * u;
    const float4* B4 = reinterpret_cast<const float4*>(Bp + (size_t)q * NS);
    float4 b0 = B4[0], b1 = B4[1];
    float Bv[8] = {b0.x, b0.y, b0.z, b0.w, b1.x, b1.y, b1.z, b1.w};
    #pragma unroll
    for (int n = 0; n < 8; ++n){
      float dA = __expf(dt * An[n]);
      h[n] = dA * h[n] + du * Bv[n];
    }
  }
  float aP[8];
  #pragma unroll
  for (int n = 0; n < 8; ++n) aP[n] = __expf(Sdt * An[n]);

  // Kogge-Stone inclusive scan of (aP,h) across 64 lanes (chunk order)
  #pragma unroll
  for (int off = 1; off < 64; off <<= 1){
    #pragma unroll
    for (int n = 0; n < 8; ++n){
      float ap = __shfl_up(aP[n], off);
      float bp = __shfl_up(h[n],  off);
      if (lane >= off){
        h[n]  = aP[n] * bp + h[n];
        aP[n] = aP[n] * ap;
      }
    }
  }
  // carry-in for this chunk = inclusive result of previous lane
  #pragma unroll
  for (int n = 0; n < 8; ++n){
    float v = __shfl_up(h[n], 1);
    h[n] = (lane == 0) ? 0.f : v;
  }
  // phase 2: rescan with carry, emit partial y into LDS
  for (int s = 0; s < CH; ++s){
    int q = s * 64 + lane;
    float dt = dtv[s];
    float u  = urow[rev ? (LL - 1 - q) : q];
    float du = dt * u;
    const float4* B4 = reinterpret_cast<const float4*>(Bp + (size_t)q * NS);
    float4 b0 = B4[0], b1 = B4[1];
    float Bv[8] = {b0.x, b0.y, b0.z, b0.w, b1.x, b1.y, b1.z, b1.w};
    const float4* C4 = reinterpret_cast<const float4*>(Cp + (size_t)q * NS);
    float4 c0 = C4[0], c1 = C4[1];
    float Cv[8] = {c0.x, c0.y, c0.z, c0.w, c1.x, c1.y, c1.z, c1.w};
    float y = 0.f;
    #pragma unroll
    for (int n = 0; n < 8; ++n){
      float dA = __expf(dt * An[n]);
      h[n] = dA * h[n] + du * Bv[n];
      y += h[n] * Cv[n];
    }
    if (nh == 0) y += Dv * u;
    int l = lane * CH + s;
    ystage[c][nh][l + l / WW] = y;
  }
  __syncthreads();
  // flush in PIXEL order (sum the two n-half partials); fold reversal and
  // transpose here. both chains of this block share the same k.
  for (int idx = threadIdx.x; idx < 2 * LL; idx += 256){
    int cc = idx / LL, qq = idx - cc * LL;
    int l;
    if      (k == 0) l = qq;
    else if (k == 1) l = (qq % WW) * WW + qq / WW;
    else if (k == 2) l = LL - 1 - qq;
    else             { int qt = (qq % WW) * WW + qq / WW; l = LL - 1 - qt; }
    int li = l + l / WW;
    y_px[(size_t)(blockIdx.x * 2 + cc) * LL + qq] = ystage[cc][0][li] + ystage[cc][1][li];
  }
}

// ------ K5: merge (4 coalesced adds) + LayerNorm + fused cross SE -------
// grid: (L/32, 2*B), block 256. y_final layout [mb][p][d]
__global__ void k_merge(const float* __restrict__ y_px, const float* __restrict__ sq,
                        const float* __restrict__ fc1_w1, const float* __restrict__ fc1_w2,
                        const float* __restrict__ fc2_w1, const float* __restrict__ fc2_w2,
                        const float* __restrict__ n1g, const float* __restrict__ n1b,
                        const float* __restrict__ n2g, const float* __restrict__ n2b,
                        float* __restrict__ y_final){
  __shared__ float acc[DIN][33];
  __shared__ float ps[8][32], ps2[8][32];
  __shared__ float mu_s[32], inv_s[32];
  __shared__ float sqs[DIN], hid[12], exc_s[DIN];
  int p0 = blockIdx.x * 32;
  int mb = blockIdx.y; int m = mb / BN, b = mb % BN;
  const float* yb = y_px + (size_t)mb * KK * DIN * LL;
  for (int idx = threadIdx.x; idx < DIN * 32; idx += 256){
    int dd = idx >> 5, pp = idx & 31;
    size_t o = (size_t)dd * LL + p0 + pp;
    acc[dd][pp] = yb[o] + yb[(size_t)DIN * LL + o]
                + yb[2 * (size_t)DIN * LL + o] + yb[3 * (size_t)DIN * LL + o];
  }
  // cross SE: y_m is scaled by exc of modality (1-m)
  int mbo = (1 - m) * BN + b;
  const float* w1 = (m == 1 ? fc1_w1 : fc2_w1);
  const float* w2 = (m == 1 ? fc1_w2 : fc2_w2);
  if (threadIdx.x < DIN) sqs[threadIdx.x] = sq[mbo * DIN + threadIdx.x];
  __syncthreads();
  if (threadIdx.x < 12){
    float a = 0.f;
    for (int cch = 0; cch < DIN; ++cch) a += w1[threadIdx.x * DIN + cch] * sqs[cch];
    hid[threadIdx.x] = a * sigmoidf_(a);
  }
  {
    int pp = threadIdx.x & 31, qr = threadIdx.x >> 5;
    float s = 0.f, s2 = 0.f;
    #pragma unroll 4
    for (int j = 0; j < 24; ++j){ float v = acc[qr * 24 + j][pp]; s += v; s2 += v * v; }
    ps[qr][pp] = s; ps2[qr][pp] = s2;
  }
  __syncthreads();
  if (threadIdx.x < 32){
    int pp = threadIdx.x;
    float s = 0.f, s2 = 0.f;
    #pragma unroll
    for (int qr = 0; qr < 8; ++qr){ s += ps[qr][pp]; s2 += ps2[qr][pp]; }
    float mu  = s * (1.0f / DIN);
    float var = s2 * (1.0f / DIN) - mu * mu;
    mu_s[pp] = mu; inv_s[pp] = rsqrtf(var + 1e-5f);
  }
  if (threadIdx.x >= 64 && threadIdx.x < 64 + DIN){
    int dd = threadIdx.x - 64;
    float e = 0.f;
    #pragma unroll
    for (int j = 0; j < 12; ++j) e += w2[dd * 12 + j] * hid[j];
    exc_s[dd] = sigmoidf_(e);
  }
  __syncthreads();
  const float* g  = (m == 0 ? n1g : n2g);
  const float* bb = (m == 0 ? n1b : n2b);
  for (int idx = threadIdx.x; idx < DIN * 32; idx += 256){
    int pp = idx / DIN, dd = idx - pp * DIN;
    float v = (acc[dd][pp] - mu_s[pp]) * inv_s[pp] * g[dd] + bb[dd];
    v *= exc_s[dd];
    y_final[((size_t)mb * LL + p0 + pp) * DIN + dd] = v;
  }
}

// ---------------- K6: out_proj (96 x 384) ----------------
// grid: (L/16, B), block 256. float4 chunks, reg-blocked 6 outputs
__global__ void k_out(const float* __restrict__ y_final, const float* __restrict__ wout,
                      float* __restrict__ out){
  __shared__ float yt[16][388];
  int p0 = blockIdx.x * 16;
  int b  = blockIdx.y;
  for (int idx = threadIdx.x; idx < 16 * 384; idx += 256){
    int pp = idx / 384, cch = idx % 384;
    int m = cch / DIN, dd = cch % DIN;
    yt[pp][cch] = y_final[(((size_t)(m * BN + b)) * LL + p0 + pp) * DIN + dd];
  }
  __syncthreads();
  int pp = threadIdx.x & 15;
  int o0 = (threadIdx.x >> 4) * 6;       // 16 groups x 6 outputs
  float acc[6];
  #pragma unroll
  for (int i = 0; i < 6; ++i) acc[i] = 0.f;
  const float4* yv = reinterpret_cast<const float4*>(yt[pp]);
  for (int cc = 0; cc < 96; ++cc){
    float4 x4 = yv[cc];
    #pragma unroll
    for (int i = 0; i < 6; ++i){
      float4 w4 = *reinterpret_cast<const float4*>(wout + (o0 + i) * 2 * DIN + cc * 4);
      acc[i] += w4.x * x4.x + w4.y * x4.y + w4.z * x4.z + w4.w * x4.w;
    }
  }
  #pragma unroll
  for (int i = 0; i < 6; ++i)
    out[((size_t)b * CIN + o0 + i) * LL + p0 + pp] = acc[i];
}

extern "C" void kernel_launch(void* const* d_in, const int* in_sizes, int n_in,
                              void* d_out, int out_size, void* d_ws, size_t ws_size,
                              hipStream_t stream){
  const float* x_rgb   = (const float*)d_in[0];
  const float* x_e     = (const float*)d_in[1];
  const float* in_w    = (const float*)d_in[2];
  const float* in_mx_w = (const float*)d_in[3];
  const float* conv_w  = (const float*)d_in[4];
  const float* conv_b  = (const float*)d_in[5];
  const float* xp1     = (const float*)d_in[6];
  const float* xp2     = (const float*)d_in[7];
  const float* dtw1    = (const float*)d_in[8];
  const float* dtb1    = (const float*)d_in[9];
  const float* dtw2    = (const float*)d_in[10];
  const float* dtb2    = (const float*)d_in[11];
  const float* Alog1   = (const float*)d_in[12];
  const float* Alog2   = (const float*)d_in[13];
  const float* D1      = (const float*)d_in[14];
  const float* D2      = (const float*)d_in[15];
  const float* n1g     = (const float*)d_in[16];
  const float* n1b     = (const float*)d_in[17];
  const float* n2g     = (const float*)d_in[18];
  const float* n2b     = (const float*)d_in[19];
  const float* fc1_w1  = (const float*)d_in[20];
  const float* fc1_w2  = (const float*)d_in[21];
  const float* fc2_w1  = (const float*)d_in[22];
  const float* fc2_w2  = (const float*)d_in[23];
  const float* wout    = (const float*)d_in[24];

  float* ws = (float*)d_ws;
  // region plan (floats), total 12,032,768 (= 48.1 MB):
  //   [0,        1228800) u_chA   (k_conv -> k_scan)
  //   [1228800,  2457600) u_chT   (k_conv -> k_scan)
  //   [2457600,  3686400) x_act   (k_conv -> k_xproj); y_final aliases after
  //   [3686400,  4915200) x_actT  (k_conv -> k_xproj)
  //   [4915200,  6144000) xproj   (k_inproj -> k_conv)
  //   [6144000, 11059200) y_px    (k_scan -> k_merge)
  //   [11059200,11468800) B_ch
  //   [11468800,11878400) C_ch
  //   [11878400,12032000) tdt_ch  [mbk][r][q]
  //   [12032000,12032768) sq
  float* u_chA   = ws;
  float* u_chT   = ws + 1228800;
  float* x_act   = ws + 2457600;
  float* x_actT  = ws + 3686400;
  float* xproj   = ws + 4915200;
  float* y_final = ws + 2457600;      // alias: x_act dead after k_xproj
  float* y_px    = ws + 6144000;
  float* B_ch    = ws + 11059200;
  float* C_ch    = ws + 11468800;
  float* tdt_ch  = ws + 11878400;
  float* sq      = ws + 12032000;

  k_inproj<<<dim3(LL / 16, 2 * BN), 256, 0, stream>>>(x_rgb, x_e, in_w, in_mx_w, xproj);
  k_conv  <<<dim3(DIN, 2 * BN), 256, 0, stream>>>(xproj, conv_w, conv_b,
                                                  x_act, x_actT, u_chA, u_chT, sq);
  k_xproj <<<dim3(LL / 64, KK, 2 * BN), 256, 0, stream>>>(x_act, x_actT, xp1, xp2,
                                                          tdt_ch, B_ch, C_ch);
  k_scan  <<<1536, 256, 0, stream>>>(u_chA, u_chT, tdt_ch, B_ch, C_ch,
                                     Alog1, Alog2, D1, D2,
                                     dtw1, dtb1, dtw2, dtb2, y_px);
  k_merge <<<dim3(LL / 32, 2 * BN), 256, 0, stream>>>(y_px, sq,
                                                      fc1_w1, fc1_w2, fc2_w1, fc2_w2,
                                                      n1g, n1b, n2g, n2b, y_final);
  k_out   <<<dim3(LL / 16, BN), 256, 0, stream>>>(y_final, wout, (float*)d_out);
}

// Round 6
// 206.163 us; speedup vs baseline: 4.8307x; 4.8307x over previous
//
#include <hip/hip_runtime.h>
#include <math.h>

#define BN   2
#define CIN  96
#define HH   40
#define WW   40
#define LL   1600
#define DIN  192
#define NS   16
#define RR   6
#define KK   4
#define CH   25   // chunk length per lane (LL/64)

__device__ __forceinline__ float sigmoidf_(float x){ return 1.0f/(1.0f+expf(-x)); }
__device__ __forceinline__ float softplus_fast(float x){
  return x > 20.0f ? x : __logf(1.0f + __expf(x));
}

// ---------------- K1: in_proj (1x1) for both modalities ----------------
// grid: (L/16, 2*B), block 256. xproj layout [mb][o][p]
__global__ void k_inproj(const float* __restrict__ x_rgb, const float* __restrict__ x_e,
                         const float* __restrict__ w_rgb, const float* __restrict__ w_e,
                         float* __restrict__ xproj){
  __shared__ float xin[16][100];          // [px][c], padded row
  int l0 = blockIdx.x * 16;
  int mb = blockIdx.y;                    // m*BN + b
  int m = mb / BN, b = mb % BN;
  const float* xsrc = (m == 0 ? x_rgb : x_e) + (size_t)b * CIN * LL;
  const float* w    = (m == 0 ? w_rgb : w_e);
  for (int idx = threadIdx.x; idx < CIN * 16; idx += 256){
    int c = idx >> 4, px = idx & 15;
    xin[px][c] = xsrc[c * LL + l0 + px];
  }
  __syncthreads();
  int px = threadIdx.x & 15;
  int o0 = (threadIdx.x >> 4) * 12;       // 16 groups x 12 outputs
  float acc[12];
  #pragma unroll
  for (int i = 0; i < 12; ++i) acc[i] = 0.f;
  const float4* xv = reinterpret_cast<const float4*>(xin[px]);
  for (int cc = 0; cc < CIN / 4; ++cc){
    float4 x4 = xv[cc];
    #pragma unroll
    for (int i = 0; i < 12; ++i){
      float4 w4 = *reinterpret_cast<const float4*>(w + (o0 + i) * CIN + cc * 4);
      acc[i] += w4.x * x4.x + w4.y * x4.y + w4.z * x4.z + w4.w * x4.w;
    }
  }
  #pragma unroll
  for (int i = 0; i < 12; ++i)
    xproj[((size_t)mb * DIN + o0 + i) * LL + l0 + px] = acc[i];
}

// ------ K2: depthwise 3x3 + bias + SiLU; emit x_act, x_actT, u_ch, SE mean ---
// grid: (DIN, 2*B), block 256
__global__ void k_conv(const float* __restrict__ xproj, const float* __restrict__ conv_w,
                       const float* __restrict__ conv_b, float* __restrict__ x_act,
                       float* __restrict__ x_actT, float* __restrict__ u_chA,
                       float* __restrict__ u_chT, float* __restrict__ sq){
  __shared__ float pl[LL];
  __shared__ float sact[LL + HH];    // padded: index l + l/40
  __shared__ float red[4];
  int d  = blockIdx.x;
  int mb = blockIdx.y;
  const float* src = xproj + ((size_t)mb * DIN + d) * LL;
  for (int p = threadIdx.x; p < LL; p += blockDim.x) pl[p] = src[p];
  __syncthreads();
  float cw[9];
  #pragma unroll
  for (int j = 0; j < 9; ++j) cw[j] = conv_w[d * 9 + j];
  float bias = conv_b[d];
  float* dst = x_act + ((size_t)mb * DIN + d) * LL;
  float lsum = 0.f;
  for (int p = threadIdx.x; p < LL; p += blockDim.x){
    int py = p / WW, px = p % WW;
    float acc = bias;
    #pragma unroll
    for (int dy = -1; dy <= 1; ++dy){
      int yy = py + dy;
      if (yy < 0 || yy >= HH) continue;
      #pragma unroll
      for (int dx = -1; dx <= 1; ++dx){
        int xx = px + dx;
        if (xx < 0 || xx >= WW) continue;
        acc += cw[(dy + 1) * 3 + (dx + 1)] * pl[yy * WW + xx];
      }
    }
    float s = acc * sigmoidf_(acc);
    dst[p] = s;
    sact[p + p / WW] = s;
    lsum += s;
  }
  #pragma unroll
  for (int off = 32; off; off >>= 1) lsum += __shfl_down(lsum, off);
  if ((threadIdx.x & 63) == 0) red[threadIdx.x >> 6] = lsum;
  __syncthreads();
  if (threadIdx.x == 0)
    sq[mb * DIN + d] = (red[0] + red[1] + red[2] + red[3]) * (1.0f / LL);
  size_t po = ((size_t)mb * DIN + d) * LL;
  float* dstT = x_actT + po;
  float* uA   = u_chA + po;
  float* uT   = u_chT + po;
  for (int q = threadIdx.x; q < LL; q += blockDim.x){
    // transposed plane (row-major in q)
    int lt = (q % WW) * WW + q / WW;
    dstT[q] = sact[lt + lt / WW];
    // chunk-order planes: q = s*64+g  <->  l = g*25+s
    int l = (q & 63) * CH + (q >> 6);
    uA[q] = sact[l + l / WW];
    int pt = (l % WW) * WW + l / WW;
    uT[q] = sact[pt + pt / WW];
  }
}

// ------ K3: x_proj -> tdt_ch [mbk][r][q]; B/C in CHUNK layout [mbk][q][n] ---
// grid: (L/64, K, 2*B), block 256
__global__ void k_xproj(const float* __restrict__ x_act, const float* __restrict__ x_actT,
                        const float* __restrict__ xp1, const float* __restrict__ xp2,
                        float* __restrict__ tdt_ch, float* __restrict__ B_ch,
                        float* __restrict__ C_ch){
  __shared__ float xs_t[DIN][64];
  int l0 = blockIdx.x * 64;
  int k  = blockIdx.y;
  int mb = blockIdx.z; int m = mb / BN;
  const float* xw = (m == 0 ? xp1 : xp2) + k * 38 * DIN;
  const float* xa = ((k & 1) ? x_actT : x_act) + (size_t)mb * DIN * LL;
  bool rev = (k >= 2);
  for (int idx = threadIdx.x; idx < DIN * 64; idx += blockDim.x){
    int dd = idx >> 6, ll = idx & 63;
    int l = l0 + ll; if (rev) l = LL - 1 - l;
    xs_t[dd][ll] = xa[dd * LL + l];
  }
  __syncthreads();
  int mbk = mb * KK + k;
  for (int oidx = threadIdx.x; oidx < 38 * 64; oidx += blockDim.x){
    int c = oidx >> 6, ll = oidx & 63;
    const float* wr = xw + c * DIN;
    float acc = 0.f;
    #pragma unroll 8
    for (int dd = 0; dd < DIN; ++dd) acc += wr[dd] * xs_t[dd][ll];
    int l = l0 + ll;
    int q = (l % CH) * 64 + l / CH;     // chunk-order index
    if (c < RR)            tdt_ch[((size_t)mbk * RR + c) * LL + q] = acc;
    else if (c < RR + NS)  B_ch[((size_t)mbk * LL + q) * NS + (c - RR)] = acc;
    else                   C_ch[((size_t)mbk * LL + q) * NS + (c - RR - NS)] = acc;
  }
}

// ---------------- K4: chunked parallel selective scan, n-split ----------
// 2 waves per chain (each owns 8 of 16 states). dt computed ONCE per chain
// (split between the two waves) into LDS — no private arrays, no scratch.
// grid: 1536 blocks of 256 (2 chains/block). y_px layout [chain][pixel]
__global__ void __launch_bounds__(256, 4) k_scan(
    const float* __restrict__ u_chA, const float* __restrict__ u_chT,
    const float* __restrict__ tdt_all, const float* __restrict__ B_ch,
    const float* __restrict__ C_ch,
    const float* __restrict__ Alog1, const float* __restrict__ Alog2,
    const float* __restrict__ D1, const float* __restrict__ D2,
    const float* __restrict__ dtw1, const float* __restrict__ dtb1,
    const float* __restrict__ dtw2, const float* __restrict__ dtb2,
    float* __restrict__ y_px){
  __shared__ float ystage[2][2][LL + HH];   // [chain-in-blk][n-half][pad l]
  __shared__ float dt_lds[2][LL];           // [chain-in-blk][q]
  int wv   = threadIdx.x >> 6;
  int lane = threadIdx.x & 63;
  int c    = wv >> 1;                       // chain in block
  int nh   = wv & 1;                        // n-half
  int chain = blockIdx.x * 2 + c;           // = (mb*KK + k)*DIN + d
  int d   = chain % DIN;
  int mbk = chain / DIN;
  int k   = mbk % KK;
  int mb  = mbk / KK;
  int m = mb / BN, b = mb % BN;
  int kd = k * DIN + d;
  bool rev = (k >= 2);

  const float* Alog = (m == 0 ? Alog1 : Alog2) + kd * NS + nh * 8;
  float An[8];
  #pragma unroll
  for (int n = 0; n < 8; ++n) An[n] = -__expf(Alog[n]);
  float Dv = (m == 0 ? D2 : D1)[kd];
  const float* dtw = (m == 0 ? dtw1 : dtw2) + kd * RR;
  float w0 = dtw[0], w1 = dtw[1], w2 = dtw[2], w3 = dtw[3], w4 = dtw[4], w5 = dtw[5];
  float dbias = (m == 0 ? dtb1 : dtb2)[kd];

  const float* t0 = tdt_all + (size_t)mbk * RR * LL;    // [r][q] rows
  const float* Bp = B_ch + (size_t)mbk * LL * NS + nh * 8;
  int mbk_o = ((1 - m) * BN + b) * KK + k;              // other modality's C
  const float* Cp = C_ch + (size_t)mbk_o * LL * NS + nh * 8;
  const float* urow = ((k & 1) ? u_chT : u_chA) + ((size_t)mb * DIN + d) * LL;

  // dt for the whole chain, computed once, split across the 2 n-half waves
  {
    int s_begin = nh ? 13 : 0;
    int s_end   = nh ? CH : 13;
    for (int s = s_begin; s < s_end; ++s){
      int q = s * 64 + lane;
      float dtpre = w0 * t0[q] + w1 * t0[LL + q] + w2 * t0[2 * LL + q]
                  + w3 * t0[3 * LL + q] + w4 * t0[4 * LL + q] + w5 * t0[5 * LL + q] + dbias;
      dt_lds[c][q] = softplus_fast(dtpre);
    }
  }
  __syncthreads();

  float h[8];
  #pragma unroll
  for (int n = 0; n < 8; ++n) h[n] = 0.f;
  float Sdt = 0.f;

  // phase 1: local chunk scan -> h_local_end; accumulate Sdt for aP
  for (int s = 0; s < CH; ++s){
    int q = s * 64 + lane;
    float dt = dt_lds[c][q];
    Sdt += dt;
    float u  = urow[rev ? (LL - 1 - q) : q];
    float du = dt * u;
    const float4* B4 = reinterpret_cast<const float4*>(Bp + (size_t)q * NS);
    float4 b0 = B4[0], b1 = B4[1];
    float Bv[8] = {b0.x, b0.y, b0.z, b0.w, b1.x, b1.y, b1.z, b1.w};
    #pragma unroll
    for (int n = 0; n < 8; ++n){
      float dA = __expf(dt * An[n]);
      h[n] = dA * h[n] + du * Bv[n];
    }
  }
  float aP[8];
  #pragma unroll
  for (int n = 0; n < 8; ++n) aP[n] = __expf(Sdt * An[n]);

  // Kogge-Stone inclusive scan of (aP,h) across 64 lanes (chunk order)
  #pragma unroll
  for (int off = 1; off < 64; off <<= 1){
    #pragma unroll
    for (int n = 0; n < 8; ++n){
      float ap = __shfl_up(aP[n], off);
      float bp = __shfl_up(h[n],  off);
      if (lane >= off){
        h[n]  = aP[n] * bp + h[n];
        aP[n] = aP[n] * ap;
      }
    }
  }
  // carry-in for this chunk = inclusive result of previous lane
  #pragma unroll
  for (int n = 0; n < 8; ++n){
    float v = __shfl_up(h[n], 1);
    h[n] = (lane == 0) ? 0.f : v;
  }
  // phase 2: rescan with carry, emit partial y into LDS
  for (int s = 0; s < CH; ++s){
    int q = s * 64 + lane;
    float dt = dt_lds[c][q];
    float u  = urow[rev ? (LL - 1 - q) : q];
    float du = dt * u;
    const float4* B4 = reinterpret_cast<const float4*>(Bp + (size_t)q * NS);
    float4 b0 = B4[0], b1 = B4[1];
    float Bv[8] = {b0.x, b0.y, b0.z, b0.w, b1.x, b1.y, b1.z, b1.w};
    const float4* C4 = reinterpret_cast<const float4*>(Cp + (size_t)q * NS);
    float4 c0 = C4[0], c1 = C4[1];
    float Cv[8] = {c0.x, c0.y, c0.z, c0.w, c1.x, c1.y, c1.z, c1.w};
    float y = 0.f;
    #pragma unroll
    for (int n = 0; n < 8; ++n){
      float dA = __expf(dt * An[n]);
      h[n] = dA * h[n] + du * Bv[n];
      y += h[n] * Cv[n];
    }
    if (nh == 0) y += Dv * u;
    int l = lane * CH + s;
    ystage[c][nh][l + l / WW] = y;
  }
  __syncthreads();
  // flush in PIXEL order (sum the two n-half partials); fold reversal and
  // transpose here. both chains of this block share the same k.
  for (int idx = threadIdx.x; idx < 2 * LL; idx += 256){
    int cc = idx / LL, qq = idx - cc * LL;
    int l;
    if      (k == 0) l = qq;
    else if (k == 1) l = (qq % WW) * WW + qq / WW;
    else if (k == 2) l = LL - 1 - qq;
    else             { int qt = (qq % WW) * WW + qq / WW; l = LL - 1 - qt; }
    int li = l + l / WW;
    y_px[(size_t)(blockIdx.x * 2 + cc) * LL + qq] = ystage[cc][0][li] + ystage[cc][1][li];
  }
}

// ------ K5: merge (4 coalesced adds) + LayerNorm + fused cross SE -------
// grid: (L/32, 2*B), block 256. y_final layout [mb][p][d]
__global__ void k_merge(const float* __restrict__ y_px, const float* __restrict__ sq,
                        const float* __restrict__ fc1_w1, const float* __restrict__ fc1_w2,
                        const float* __restrict__ fc2_w1, const float* __restrict__ fc2_w2,
                        const float* __restrict__ n1g, const float* __restrict__ n1b,
                        const float* __restrict__ n2g, const float* __restrict__ n2b,
                        float* __restrict__ y_final){
  __shared__ float acc[DIN][33];
  __shared__ float ps[8][32], ps2[8][32];
  __shared__ float mu_s[32], inv_s[32];
  __shared__ float sqs[DIN], hid[12], exc_s[DIN];
  int p0 = blockIdx.x * 32;
  int mb = blockIdx.y; int m = mb / BN, b = mb % BN;
  const float* yb = y_px + (size_t)mb * KK * DIN * LL;
  for (int idx = threadIdx.x; idx < DIN * 32; idx += 256){
    int dd = idx >> 5, pp = idx & 31;
    size_t o = (size_t)dd * LL + p0 + pp;
    acc[dd][pp] = yb[o] + yb[(size_t)DIN * LL + o]
                + yb[2 * (size_t)DIN * LL + o] + yb[3 * (size_t)DIN * LL + o];
  }
  // cross SE: y_m is scaled by exc of modality (1-m)
  int mbo = (1 - m) * BN + b;
  const float* w1 = (m == 1 ? fc1_w1 : fc2_w1);
  const float* w2 = (m == 1 ? fc1_w2 : fc2_w2);
  if (threadIdx.x < DIN) sqs[threadIdx.x] = sq[mbo * DIN + threadIdx.x];
  __syncthreads();
  if (threadIdx.x < 12){
    float a = 0.f;
    for (int cch = 0; cch < DIN; ++cch) a += w1[threadIdx.x * DIN + cch] * sqs[cch];
    hid[threadIdx.x] = a * sigmoidf_(a);
  }
  {
    int pp = threadIdx.x & 31, qr = threadIdx.x >> 5;
    float s = 0.f, s2 = 0.f;
    #pragma unroll 4
    for (int j = 0; j < 24; ++j){ float v = acc[qr * 24 + j][pp]; s += v; s2 += v * v; }
    ps[qr][pp] = s; ps2[qr][pp] = s2;
  }
  __syncthreads();
  if (threadIdx.x < 32){
    int pp = threadIdx.x;
    float s = 0.f, s2 = 0.f;
    #pragma unroll
    for (int qr = 0; qr < 8; ++qr){ s += ps[qr][pp]; s2 += ps2[qr][pp]; }
    float mu  = s * (1.0f / DIN);
    float var = s2 * (1.0f / DIN) - mu * mu;
    mu_s[pp] = mu; inv_s[pp] = rsqrtf(var + 1e-5f);
  }
  if (threadIdx.x >= 64 && threadIdx.x < 64 + DIN){
    int dd = threadIdx.x - 64;
    float e = 0.f;
    #pragma unroll
    for (int j = 0; j < 12; ++j) e += w2[dd * 12 + j] * hid[j];
    exc_s[dd] = sigmoidf_(e);
  }
  __syncthreads();
  const float* g  = (m == 0 ? n1g : n2g);
  const float* bb = (m == 0 ? n1b : n2b);
  for (int idx = threadIdx.x; idx < DIN * 32; idx += 256){
    int pp = idx / DIN, dd = idx - pp * DIN;
    float v = (acc[dd][pp] - mu_s[pp]) * inv_s[pp] * g[dd] + bb[dd];
    v *= exc_s[dd];
    y_final[((size_t)mb * LL + p0 + pp) * DIN + dd] = v;
  }
}

// ---------------- K6: out_proj (96 x 384) ----------------
// grid: (L/16, B), block 256. float4 chunks, reg-blocked 6 outputs
__global__ void k_out(const float* __restrict__ y_final, const float* __restrict__ wout,
                      float* __restrict__ out){
  __shared__ float yt[16][388];
  int p0 = blockIdx.x * 16;
  int b  = blockIdx.y;
  for (int idx = threadIdx.x; idx < 16 * 384; idx += 256){
    int pp = idx / 384, cch = idx % 384;
    int m = cch / DIN, dd = cch % DIN;
    yt[pp][cch] = y_final[(((size_t)(m * BN + b)) * LL + p0 + pp) * DIN + dd];
  }
  __syncthreads();
  int pp = threadIdx.x & 15;
  int o0 = (threadIdx.x >> 4) * 6;       // 16 groups x 6 outputs
  float acc[6];
  #pragma unroll
  for (int i = 0; i < 6; ++i) acc[i] = 0.f;
  const float4* yv = reinterpret_cast<const float4*>(yt[pp]);
  for (int cc = 0; cc < 96; ++cc){
    float4 x4 = yv[cc];
    #pragma unroll
    for (int i = 0; i < 6; ++i){
      float4 w4 = *reinterpret_cast<const float4*>(wout + (o0 + i) * 2 * DIN + cc * 4);
      acc[i] += w4.x * x4.x + w4.y * x4.y + w4.z * x4.z + w4.w * x4.w;
    }
  }
  #pragma unroll
  for (int i = 0; i < 6; ++i)
    out[((size_t)b * CIN + o0 + i) * LL + p0 + pp] = acc[i];
}

extern "C" void kernel_launch(void* const* d_in, const int* in_sizes, int n_in,
                              void* d_out, int out_size, void* d_ws, size_t ws_size,
                              hipStream_t stream){
  const float* x_rgb   = (const float*)d_in[0];
  const float* x_e     = (const float*)d_in[1];
  const float* in_w    = (const float*)d_in[2];
  const float* in_mx_w = (const float*)d_in[3];
  const float* conv_w  = (const float*)d_in[4];
  const float* conv_b  = (const float*)d_in[5];
  const float* xp1     = (const float*)d_in[6];
  const float* xp2     = (const float*)d_in[7];
  const float* dtw1    = (const float*)d_in[8];
  const float* dtb1    = (const float*)d_in[9];
  const float* dtw2    = (const float*)d_in[10];
  const float* dtb2    = (const float*)d_in[11];
  const float* Alog1   = (const float*)d_in[12];
  const float* Alog2   = (const float*)d_in[13];
  const float* D1      = (const float*)d_in[14];
  const float* D2      = (const float*)d_in[15];
  const float* n1g     = (const float*)d_in[16];
  const float* n1b     = (const float*)d_in[17];
  const float* n2g     = (const float*)d_in[18];
  const float* n2b     = (const float*)d_in[19];
  const float* fc1_w1  = (const float*)d_in[20];
  const float* fc1_w2  = (const float*)d_in[21];
  const float* fc2_w1  = (const float*)d_in[22];
  const float* fc2_w2  = (const float*)d_in[23];
  const float* wout    = (const float*)d_in[24];

  float* ws = (float*)d_ws;
  // region plan (floats), total 12,032,768 (= 48.1 MB):
  //   [0,        1228800) u_chA   (k_conv -> k_scan)
  //   [1228800,  2457600) u_chT   (k_conv -> k_scan)
  //   [2457600,  3686400) x_act   (k_conv -> k_xproj); y_final aliases after
  //   [3686400,  4915200) x_actT  (k_conv -> k_xproj)
  //   [4915200,  6144000) xproj   (k_inproj -> k_conv)
  //   [6144000, 11059200) y_px    (k_scan -> k_merge)
  //   [11059200,11468800) B_ch
  //   [11468800,11878400) C_ch
  //   [11878400,12032000) tdt_ch  [mbk][r][q]
  //   [12032000,12032768) sq
  float* u_chA   = ws;
  float* u_chT   = ws + 1228800;
  float* x_act   = ws + 2457600;
  float* x_actT  = ws + 3686400;
  float* xproj   = ws + 4915200;
  float* y_final = ws + 2457600;      // alias: x_act dead after k_xproj
  float* y_px    = ws + 6144000;
  float* B_ch    = ws + 11059200;
  float* C_ch    = ws + 11468800;
  float* tdt_ch  = ws + 11878400;
  float* sq      = ws + 12032000;

  k_inproj<<<dim3(LL / 16, 2 * BN), 256, 0, stream>>>(x_rgb, x_e, in_w, in_mx_w, xproj);
  k_conv  <<<dim3(DIN, 2 * BN), 256, 0, stream>>>(xproj, conv_w, conv_b,
                                                  x_act, x_actT, u_chA, u_chT, sq);
  k_xproj <<<dim3(LL / 64, KK, 2 * BN), 256, 0, stream>>>(x_act, x_actT, xp1, xp2,
                                                          tdt_ch, B_ch, C_ch);
  k_scan  <<<1536, 256, 0, stream>>>(u_chA, u_chT, tdt_ch, B_ch, C_ch,
                                     Alog1, Alog2, D1, D2,
                                     dtw1, dtb1, dtw2, dtb2, y_px);
  k_merge <<<dim3(LL / 32, 2 * BN), 256, 0, stream>>>(y_px, sq,
                                                      fc1_w1, fc1_w2, fc2_w1, fc2_w2,
                                                      n1g, n1b, n2g, n2b, y_final);
  k_out   <<<dim3(LL / 16, BN), 256, 0, stream>>>(y_final, wout, (float*)d_out);
}